// Round 1
// baseline (390.117 us; speedup 1.0000x reference)
//
#include <hip/hip_runtime.h>

// GeneralConvNd: 7x7 single-in-channel conv, 64 out channels, 'same' padding.
// out[b,h,w,c] = sum_{ky,kx} x[b,h+ky-3,w+kx-3] * W[ky*7+kx, c] + bias[c]
//
// Design: lane = output channel c (64 lanes). W[k][lane] lives in 49 VGPRs per
// wave, loaded ONCE and reused across 18 grid-strided runs (re-loading per run
// would be ~37 TB/s of L1 traffic). Each run = 8 consecutive pixels along w at
// fixed (b,h). The 7x14 x-halo is fetched with 2 coalesced vector loads, then
// broadcast to SGPRs via v_readlane (SALU pipe — hidden under the 392 fmacs).
// v_fmac_f32 takes the uniform x value as its one allowed scalar operand.
// Stores: 64 lanes x dword = 256 B contiguous per pixel, fully coalesced.

#define KS 7
#define COUTC 64
#define HH 384
#define WWID 384
#define BB 8
#define PRUN 8
#define RUNS_PER_ROW (WWID / PRUN)            // 48
#define NRUNS (BB * HH * RUNS_PER_ROW)        // 147456
#define NBLOCKS 2048
#define WAVES_PER_BLOCK 4
#define TOTAL_WAVES (NBLOCKS * WAVES_PER_BLOCK)   // 8192 -> exactly 18 runs/wave

__device__ __forceinline__ float rl(float v, int l) {
    return __int_as_float(__builtin_amdgcn_readlane(__float_as_int(v), l));
}

__global__ __launch_bounds__(256)
void conv7x7_c64_kernel(const float* __restrict__ xg,
                        const float* __restrict__ wg,
                        const float* __restrict__ bg,
                        float* __restrict__ out)
{
    const int lane  = threadIdx.x & 63;
    const int wave  = threadIdx.x >> 6;
    const int gwave = blockIdx.x * WAVES_PER_BLOCK + wave;

    // W[k][lane] resident in VGPRs for the whole kernel (lane = channel).
    float wreg[49];
#pragma unroll
    for (int k = 0; k < 49; ++k) wreg[k] = wg[k * COUTC + lane];
    const float bias = bg[lane];

    // Halo-load lane mapping: v0 covers rows 0..3 of the 7x14 patch window
    // (lane = row*16 + col), v1 covers rows 4..6. Cols 14,15 unused.
    const int row0 = lane >> 4;       // 0..3
    const int col  = lane & 15;       // 0..15
    const bool colin = (col < 14);

    for (int run = gwave; run < NRUNS; run += TOTAL_WAVES) {
        const int r  = run % RUNS_PER_ROW;
        const int hb = run / RUNS_PER_ROW;
        const int h  = hb % HH;
        const int b  = hb / HH;
        const int w0 = r * PRUN;

        const float* xb = xg + b * (HH * WWID);
        const int  ww  = w0 - 3 + col;
        const bool cok = colin && (ww >= 0) && (ww < WWID);
        const int  h0  = h - 3 + row0;            // rows h-3 .. h
        const int  h1  = h + 1 + row0;            // rows h+1 .. h+3 (row0<3)
        float v0 = 0.f, v1 = 0.f;
        if (cok && h0 >= 0 && h0 < HH) v0 = xb[h0 * WWID + ww];
        if (cok && row0 < 3 && h1 < HH) v1 = xb[h1 * WWID + ww];

        float acc[PRUN];
#pragma unroll
        for (int p = 0; p < PRUN; ++p) acc[p] = bias;

#pragma unroll
        for (int dy = 0; dy < 7; ++dy) {
            // Broadcast this patch row (14 cols) to uniform values via readlane.
            float xs[14];
#pragma unroll
            for (int c = 0; c < 14; ++c) {
                xs[c] = (dy < 4) ? rl(v0, dy * 16 + c)
                                 : rl(v1, (dy - 4) * 16 + c);
            }
#pragma unroll
            for (int dx = 0; dx < 7; ++dx) {
                const float wv = wreg[dy * 7 + dx];
#pragma unroll
                for (int p = 0; p < PRUN; ++p)
                    acc[p] = fmaf(xs[dx + p], wv, acc[p]);
            }
        }

        float* op = out + (((size_t)b * HH + h) * WWID + w0) * COUTC + lane;
#pragma unroll
        for (int p = 0; p < PRUN; ++p) op[p * COUTC] = acc[p];
    }
}

extern "C" void kernel_launch(void* const* d_in, const int* in_sizes, int n_in,
                              void* d_out, int out_size, void* d_ws, size_t ws_size,
                              hipStream_t stream) {
    const float* x = (const float*)d_in[0];   // [8,384,384]
    const float* w = (const float*)d_in[1];   // [49,64]
    const float* b = (const float*)d_in[2];   // [64]
    float* out = (float*)d_out;               // [8,384,384,64]
    (void)in_sizes; (void)n_in; (void)out_size; (void)d_ws; (void)ws_size;
    conv7x7_c64_kernel<<<NBLOCKS, 256, 0, stream>>>(x, w, b, out);
}

// Round 2
// 330.549 us; speedup vs baseline: 1.1802x; 1.1802x over previous
//
#include <hip/hip_runtime.h>

// GeneralConvNd as implicit GEMM: patches[B*H*W x 49] @ W[49 x 64], bf16 MFMA
// (fp32 accumulate). out[b,h,w,c] = sum_{ky,kx} x[b,h+ky-3,w+kx-3]*W[ky*7+kx,c]+b[c]
//
// Tiling: block = 4 waves x 16 px = 64 consecutive pixels at fixed (b,h).
// Grid-stride: 2048 blocks x 9 tiles (18432 tiles exactly). Per tile the block
// stages the 7x70 f32 halo as bf16 into LDS [10][72]; rows 7..9 are zeroed once
// so the K-padding taps (k=49..63) read 0 (W frags there are 0 too).
// Per wave: 8x mfma_f32_16x16x32_bf16 (2 K-chunks x 4 chan-groups). B-frags +
// bias loaded once per block (amortized over 9 tiles). A-frags: 16 ds_read_u16
// at loop-invariant precomputed offsets. C/D layout (m89-verified):
// chan = g*16 + (lane&15), pixel = (lane>>4)*4 + reg.
// bf16 error budget: ~0.01-0.03 absmax vs 0.138 threshold.

#define HH 384
#define WWID 384
#define BB 8
#define COUTC 64
#define TPX 64
#define TILES_PER_ROW 6                      // 384/64
#define NTILES (BB * HH * TILES_PER_ROW)     // 18432
#define NBLOCKS 2048
#define TILES_PER_BLOCK (NTILES / NBLOCKS)   // 9 exactly

typedef __attribute__((ext_vector_type(8))) __bf16 bf16x8;
typedef __attribute__((ext_vector_type(4))) float f32x4;

__global__ __launch_bounds__(256)
void conv7_mfma(const float* __restrict__ xg, const float* __restrict__ wg,
                const float* __restrict__ bg, float* __restrict__ out)
{
    __shared__ __bf16 xt[10][72];
    const int tid  = threadIdx.x;
    const int lane = tid & 63;
    const int wv   = tid >> 6;     // wave 0..3
    const int lq   = lane >> 4;    // 0..3
    const int lr   = lane & 15;    // 0..15

    // ---- B fragments + bias: loaded ONCE per block ----
    bf16x8 bfr[2][4];
#pragma unroll
    for (int ch = 0; ch < 2; ++ch)
#pragma unroll
        for (int g = 0; g < 4; ++g) {
            bf16x8 f;
#pragma unroll
            for (int j = 0; j < 8; ++j) {
                const int k = ch * 32 + lq * 8 + j;
                f[j] = (k < 49) ? (__bf16)wg[k * COUTC + g * 16 + lr] : (__bf16)0.f;
            }
            bfr[ch][g] = f;
        }
    float biasv[4];
#pragma unroll
    for (int g = 0; g < 4; ++g) biasv[g] = bg[g * 16 + lr];

    // ---- loop-invariant A-frag LDS element offsets ----
    int aoffp[2][8];
#pragma unroll
    for (int ch = 0; ch < 2; ++ch)
#pragma unroll
        for (int j = 0; j < 8; ++j) {
            const int k  = ch * 32 + lq * 8 + j;    // 0..63
            const int ky = k / 7, kx = k - ky * 7;  // ky<=9 kx<=6
            aoffp[ch][j] = ky * 72 + kx + wv * 16 + lr;
        }

    // zero LDS K-padding rows 7..9 (ordered before first read by stage barrier)
    for (int i = tid; i < 3 * 72; i += 256)
        (&xt[0][0])[7 * 72 + i] = (__bf16)0.f;

    for (int it = 0; it < TILES_PER_BLOCK; ++it) {
        const int tile = blockIdx.x * TILES_PER_BLOCK + it;  // consecutive -> L2 locality
        const int t  = tile % TILES_PER_ROW;
        const int rh = tile / TILES_PER_ROW;
        const int h  = rh % HH;
        const int b  = rh / HH;
        const int w0 = t * TPX;

        __syncthreads();   // previous tile's readers done before overwrite
        // stage rows 0..6, cols 0..69 of the halo (zero-fill OOB)
        for (int i = tid; i < 490; i += 256) {
            const int r  = i / 70;
            const int c  = i - r * 70;
            const int hs = h - 3 + r;
            const int ws = w0 - 3 + c;
            float v = 0.f;
            if (hs >= 0 && hs < HH && ws >= 0 && ws < WWID)
                v = xg[((size_t)b * HH + hs) * WWID + ws];
            xt[r][c] = (__bf16)v;
        }
        __syncthreads();

        // A fragments: 16 ds_read_u16 at precomputed offsets
        bf16x8 af[2];
#pragma unroll
        for (int ch = 0; ch < 2; ++ch) {
            bf16x8 f;
#pragma unroll
            for (int j = 0; j < 8; ++j)
                f[j] = (&xt[0][0])[aoffp[ch][j]];
            af[ch] = f;
        }

        f32x4 acc[4];
#pragma unroll
        for (int g = 0; g < 4; ++g)
            acc[g] = (f32x4){biasv[g], biasv[g], biasv[g], biasv[g]};
#pragma unroll
        for (int ch = 0; ch < 2; ++ch)
#pragma unroll
            for (int g = 0; g < 4; ++g)
                acc[g] = __builtin_amdgcn_mfma_f32_16x16x32_bf16(
                    af[ch], bfr[ch][g], acc[g], 0, 0, 0);

        // store: pixel = w0 + wv*16 + lq*4 + reg, chan = g*16 + lr
        float* obase = out + (((size_t)b * HH + h) * WWID + w0 + wv * 16) * COUTC;
#pragma unroll
        for (int g = 0; g < 4; ++g)
#pragma unroll
            for (int rr = 0; rr < 4; ++rr)
                obase[(size_t)(lq * 4 + rr) * COUTC + g * 16 + lr] = acc[g][rr];
    }
}

extern "C" void kernel_launch(void* const* d_in, const int* in_sizes, int n_in,
                              void* d_out, int out_size, void* d_ws, size_t ws_size,
                              hipStream_t stream) {
    const float* x = (const float*)d_in[0];   // [8,384,384]
    const float* w = (const float*)d_in[1];   // [49,64]
    const float* b = (const float*)d_in[2];   // [64]
    float* out = (float*)d_out;               // [8,384,384,64] f32
    (void)in_sizes; (void)n_in; (void)out_size; (void)d_ws; (void)ws_size;
    conv7_mfma<<<NBLOCKS, 256, 0, stream>>>(x, w, b, out);
}